// Round 1
// baseline (114.095 us; speedup 1.0000x reference)
//
#include <hip/hip_runtime.h>
#include <hip/hip_bf16.h>

// DynamicQAgent: B=4096 sessions, T=1000 steps, sequential nonlinear scan per
// session, parallel across sessions. Exploits exact 0/1 inputs:
//   sel_L one-hot at j = 2*(1-choice) + (1-outcome); sel_R one-hot at j^2;
//   lam columns are always equal (scalar lam per session);
//   lam-update operand gdiffs[j] == (j<2 ? dL : dR).
// Pass 1: pack j codes (2 bits/step, 8 steps per u32) into d_ws, [word][b]
//         layout so pass-2 reads are coalesced.
// Pass 2: one thread per session, 64 blocks x 64 threads (1 wave/CU spread).

constexpr int BS = 4096;   // sessions
constexpr int TS = 1000;   // timesteps
constexpr int SPW = 8;     // steps per packed u32 (2 bits each, low 16 bits)
constexpr int NW = TS / SPW; // 125 words per session

__device__ __forceinline__ float sigmoidf_(float x) {
    return 1.0f / (1.0f + expf(-x));
}

struct Params {
    float k0, k1, k2, k3;
    float a0, a1, a2, a3;
    float g0, g1;
};

// --- pass 1: pack 8 steps (24 floats = 6 float4) into one u32 of 2-bit codes
__global__ __launch_bounds__(256) void pack_kernel(const float* __restrict__ inp,
                                                   unsigned int* __restrict__ packed) {
    int tid = blockIdx.x * blockDim.x + threadIdx.x;
    if (tid >= BS * NW) return;
    int b = tid / NW;
    int w = tid - b * NW;
    const float4* p = reinterpret_cast<const float4*>(inp + (size_t)b * (3 * TS) + (size_t)w * 24);
    float4 q0 = p[0], q1 = p[1], q2 = p[2], q3 = p[3], q4 = p[4], q5 = p[5];
    // step i: choice at flat 3i, outcome at flat 3i+2
    float c[8] = {q0.x, q0.w, q1.z, q2.y, q3.x, q3.w, q4.z, q5.y};
    float o[8] = {q0.z, q1.y, q2.x, q2.w, q3.z, q4.y, q5.x, q5.w};
    unsigned word = 0;
#pragma unroll
    for (int i = 0; i < 8; ++i) {
        unsigned j = ((c[i] == 0.0f) ? 2u : 0u) | ((o[i] == 0.0f) ? 1u : 0u);
        word |= j << (2 * i);
    }
    packed[(size_t)w * BS + b] = word;
}

// --- 8 scan steps from one packed word
__device__ __forceinline__ void steps8(unsigned word, float& sL, float& sR, float& lam,
                                       const Params& P, float* __restrict__ op) {
#pragma unroll
    for (int i = 0; i < 8; ++i) {
        unsigned j = (word >> (2 * i)) & 3u;
        bool b0 = (j & 1u) != 0u;  // outcome == 0
        bool b1 = (j & 2u) != 0u;  // choice  == 0
        float k_lo = b0 ? P.k1 : P.k0;
        float k_hi = b0 ? P.k3 : P.k2;
        float a_lo = b0 ? P.a1 : P.a0;
        float a_hi = b0 ? P.a3 : P.a2;
        float gb   = b0 ? P.g1 : P.g0;
        float kj   = b1 ? k_hi : k_lo;
        float kjR  = b1 ? k_lo : k_hi;
        float aj   = b1 ? a_hi : a_lo;
        float ajR  = b1 ? a_lo : a_hi;
        float dL = kj - sL;          // uses OLD state
        float dR = kjR - sR;
        float v  = b1 ? dR : dL;     // gdiffs[j], old state
        sL = fmaf(dL * aj, lam, sL); // state + (dLj*aj)*lam
        sR = fmaf(dR * ajR, lam, sR);
        lam = fmaf(fabsf(v) - lam, gb, lam);
        reinterpret_cast<float2*>(op)[i] = make_float2(sL, sR);
    }
}

__device__ __forceinline__ Params load_params(const float* __restrict__ alpha_logits,
                                              const float* __restrict__ gamma_logits,
                                              const float* __restrict__ k_vals) {
    Params P;
    P.a0 = sigmoidf_(alpha_logits[0]);
    P.a1 = sigmoidf_(alpha_logits[1]);
    P.a2 = sigmoidf_(alpha_logits[2]);
    P.a3 = sigmoidf_(alpha_logits[3]);
    P.g0 = sigmoidf_(gamma_logits[0]);
    P.g1 = sigmoidf_(gamma_logits[1]);
    P.k0 = k_vals[0];
    P.k1 = k_vals[1];
    P.k2 = k_vals[2];
    P.k3 = k_vals[3];
    return P;
}

// --- pass 2: sequential scan, one thread per session
__global__ __launch_bounds__(64) void scan_packed(const unsigned int* __restrict__ packed,
                                                  const float* __restrict__ alpha_logits,
                                                  const float* __restrict__ gamma_logits,
                                                  const float* __restrict__ k_vals,
                                                  float* __restrict__ out) {
    int b = blockIdx.x * 64 + threadIdx.x;
    Params P = load_params(alpha_logits, gamma_logits, k_vals);
    float sL = 0.0f, sR = 0.0f, lam = 0.5f;
    float* op = out + (size_t)b * (2 * TS);
    for (int w = 0; w < NW; ++w) {
        unsigned word = packed[(size_t)w * BS + b];
        steps8(word, sL, sR, lam, P, op);
        op += 16;
    }
}

// --- fallback if ws too small: read inp directly (uncoalesced but correct)
__global__ __launch_bounds__(64) void scan_fused(const float* __restrict__ inp,
                                                 const float* __restrict__ alpha_logits,
                                                 const float* __restrict__ gamma_logits,
                                                 const float* __restrict__ k_vals,
                                                 float* __restrict__ out) {
    int b = blockIdx.x * 64 + threadIdx.x;
    Params P = load_params(alpha_logits, gamma_logits, k_vals);
    float sL = 0.0f, sR = 0.0f, lam = 0.5f;
    float* op = out + (size_t)b * (2 * TS);
    for (int w = 0; w < NW; ++w) {
        const float4* p = reinterpret_cast<const float4*>(inp + (size_t)b * (3 * TS) + (size_t)w * 24);
        float4 q0 = p[0], q1 = p[1], q2 = p[2], q3 = p[3], q4 = p[4], q5 = p[5];
        float c[8] = {q0.x, q0.w, q1.z, q2.y, q3.x, q3.w, q4.z, q5.y};
        float o[8] = {q0.z, q1.y, q2.x, q2.w, q3.z, q4.y, q5.x, q5.w};
        unsigned word = 0;
#pragma unroll
        for (int i = 0; i < 8; ++i) {
            unsigned j = ((c[i] == 0.0f) ? 2u : 0u) | ((o[i] == 0.0f) ? 1u : 0u);
            word |= j << (2 * i);
        }
        steps8(word, sL, sR, lam, P, op);
        op += 16;
    }
}

extern "C" void kernel_launch(void* const* d_in, const int* in_sizes, int n_in,
                              void* d_out, int out_size, void* d_ws, size_t ws_size,
                              hipStream_t stream) {
    const float* inp          = (const float*)d_in[0];
    const float* alpha_logits = (const float*)d_in[1];
    const float* gamma_logits = (const float*)d_in[2];
    const float* k_vals       = (const float*)d_in[3];
    float* out = (float*)d_out;

    size_t need = (size_t)NW * BS * sizeof(unsigned int);
    if (ws_size >= need) {
        unsigned int* packed = (unsigned int*)d_ws;
        int total = BS * NW;
        pack_kernel<<<(total + 255) / 256, 256, 0, stream>>>(inp, packed);
        scan_packed<<<BS / 64, 64, 0, stream>>>(packed, alpha_logits, gamma_logits, k_vals, out);
    } else {
        scan_fused<<<BS / 64, 64, 0, stream>>>(inp, alpha_logits, gamma_logits, k_vals, out);
    }
}

// Round 2
// 77.943 us; speedup vs baseline: 1.4638x; 1.4638x over previous
//
#include <hip/hip_runtime.h>
#include <hip/hip_bf16.h>

// DynamicQAgent: B=4096 sessions, T=1000 steps. Sequential nonlinear scan in T,
// parallel in B (only 64 waves exist -> latency/issue-bound regime).
//
// R2 changes vs R1 (which was store-scatter-bound: VALUBusy 2.3%, 101us):
//  1. LDS-staged coalesced output: 64 steps buffered per session, flushed as
//     64-lane contiguous 512B stores (8 lines/instr vs 64 scattered).
//  2. Packed codes laid out [g4][session][uint4]: 32 steps per dwordx4 load.
//  3. 4-entry LDS LUT (k[j], k[j^2], a[j], a[j^2], g[j&1]) replaces ~12
//     cmp/cndmask per step with 2 ds_reads.

constexpr int BS = 4096;    // sessions
constexpr int TS = 1000;    // timesteps
constexpr int NW = 125;     // real packed words (8 steps each)
constexpr int NG4 = 32;     // uint4 groups (128 words, padded)
constexpr int CHUNKB = 520; // LDS bytes per session chunk (512 + 8 pad)
constexpr int NFLUSH = 16;  // 128 words / 8 words-per-flush

__device__ __forceinline__ float sigmoidf_(float x) {
    return 1.0f / (1.0f + expf(-x));
}

// --- pass 1: pack 8 steps (24 floats = 6 float4) into one u32 of 2-bit codes.
// Layout: packed[(w>>2)*(BS*4) + b*4 + (w&3)] so scan loads uint4 per 4 words.
__global__ __launch_bounds__(256) void pack_kernel(const float* __restrict__ inp,
                                                   unsigned int* __restrict__ packed) {
    int tid = blockIdx.x * blockDim.x + threadIdx.x;
    if (tid >= BS * NW) return;
    int b = tid / NW;
    int w = tid - b * NW;
    const float4* p = reinterpret_cast<const float4*>(inp + (size_t)b * (3 * TS) + (size_t)w * 24);
    float4 q0 = p[0], q1 = p[1], q2 = p[2], q3 = p[3], q4 = p[4], q5 = p[5];
    float c[8] = {q0.x, q0.w, q1.z, q2.y, q3.x, q3.w, q4.z, q5.y};
    float o[8] = {q0.z, q1.y, q2.x, q2.w, q3.z, q4.y, q5.x, q5.w};
    unsigned word = 0;
#pragma unroll
    for (int i = 0; i < 8; ++i) {
        unsigned j = ((c[i] == 0.0f) ? 2u : 0u) | ((o[i] == 0.0f) ? 1u : 0u);
        word |= j << (2 * i);
    }
    packed[(size_t)(w >> 2) * (BS * 4) + (size_t)b * 4 + (w & 3)] = word;
}

// --- pass 2: scan. One wave (64 threads) per block, 64 blocks. Thread=session.
__global__ __launch_bounds__(64) void scan2(const uint4* __restrict__ packed4,
                                            const float* __restrict__ alpha_logits,
                                            const float* __restrict__ gamma_logits,
                                            const float* __restrict__ k_vals,
                                            float* __restrict__ out) {
    __shared__ float lut[4][8];                       // j: k[j], k[j^2], a[j], a[j^2], g[j&1]
    __shared__ unsigned char chunks[64 * CHUNKB];     // 33.3 KB staging

    const int l = threadIdx.x;
    const int b = blockIdx.x * 64 + l;

    if (l < 4) {
        int j = l;
        float k0 = k_vals[0], k1 = k_vals[1], k2 = k_vals[2], k3 = k_vals[3];
        float a0 = sigmoidf_(alpha_logits[0]), a1 = sigmoidf_(alpha_logits[1]);
        float a2 = sigmoidf_(alpha_logits[2]), a3 = sigmoidf_(alpha_logits[3]);
        float g0 = sigmoidf_(gamma_logits[0]), g1 = sigmoidf_(gamma_logits[1]);
        float kk[4] = {k0, k1, k2, k3};
        float aa[4] = {a0, a1, a2, a3};
        float gg[2] = {g0, g1};
        lut[j][0] = kk[j];
        lut[j][1] = kk[j ^ 2];
        lut[j][2] = aa[j];
        lut[j][3] = aa[j ^ 2];
        lut[j][4] = gg[j & 1];
    }
    __syncthreads();

    float sL = 0.0f, sR = 0.0f, lam = 0.5f;
    unsigned char* mychunk = chunks + l * CHUNKB;
    const uint4* pp = packed4 + b;   // + g4 * BS per group

    for (int f = 0; f < NFLUSH; ++f) {
        // 2 x uint4 = 64 steps worth of codes, coalesced 1KB wave reads
        uint4 wa = pp[(size_t)(2 * f) * BS];
        uint4 wb = pp[(size_t)(2 * f + 1) * BS];
        unsigned words[8] = {wa.x, wa.y, wa.z, wa.w, wb.x, wb.y, wb.z, wb.w};

        for (int q = 0; q < 8; ++q) {
            unsigned word = words[q];
            float2* slot = reinterpret_cast<float2*>(mychunk + q * 64);
#pragma unroll
            for (int i = 0; i < 8; ++i) {
                unsigned j = (word >> (2 * i)) & 3u;
                const float4 e = *reinterpret_cast<const float4*>(&lut[j][0]);
                const float gb = lut[j][4];
                float dL = e.x - sL;          // k[j]   - sL
                float dR = e.y - sR;          // k[j^2] - sR
                float v = (j >= 2u) ? dR : dL;
                sL = fmaf(dL * e.z, lam, sL); // + dL*a[j]  *lam
                sR = fmaf(dR * e.w, lam, sR); // + dR*a[j^2]*lam
                lam = fmaf(fabsf(v) - lam, gb, lam);
                slot[i] = make_float2(sL, sR);
            }
        }
        __syncthreads();

        // flush: per session, 64 lanes store contiguous 512B (float2 each)
        const int nws = (f == NFLUSH - 1) ? (NW - (NFLUSH - 1) * 8) : 8; // 8 or 5
        const bool act = (l < nws * 8);
        const size_t obase = (size_t)blockIdx.x * 64 * (2 * TS) + (size_t)f * 128 + (size_t)l * 2;
#pragma unroll 8
        for (int s = 0; s < 64; ++s) {
            float2 v2 = *reinterpret_cast<const float2*>(chunks + s * CHUNKB + l * 8);
            if (act) {
                *reinterpret_cast<float2*>(out + obase + (size_t)s * (2 * TS)) = v2;
            }
        }
        __syncthreads();
    }
}

// --- fallback if ws too small: read inp directly (uncoalesced but correct)
__global__ __launch_bounds__(64) void scan_fused(const float* __restrict__ inp,
                                                 const float* __restrict__ alpha_logits,
                                                 const float* __restrict__ gamma_logits,
                                                 const float* __restrict__ k_vals,
                                                 float* __restrict__ out) {
    int b = blockIdx.x * 64 + threadIdx.x;
    float a0 = sigmoidf_(alpha_logits[0]), a1 = sigmoidf_(alpha_logits[1]);
    float a2 = sigmoidf_(alpha_logits[2]), a3 = sigmoidf_(alpha_logits[3]);
    float g0 = sigmoidf_(gamma_logits[0]), g1 = sigmoidf_(gamma_logits[1]);
    float k0 = k_vals[0], k1 = k_vals[1], k2 = k_vals[2], k3 = k_vals[3];
    float sL = 0.0f, sR = 0.0f, lam = 0.5f;
    float* op = out + (size_t)b * (2 * TS);
    for (int w = 0; w < NW; ++w) {
        const float4* p = reinterpret_cast<const float4*>(inp + (size_t)b * (3 * TS) + (size_t)w * 24);
        float4 q0 = p[0], q1 = p[1], q2 = p[2], q3 = p[3], q4 = p[4], q5 = p[5];
        float c[8] = {q0.x, q0.w, q1.z, q2.y, q3.x, q3.w, q4.z, q5.y};
        float o[8] = {q0.z, q1.y, q2.x, q2.w, q3.z, q4.y, q5.x, q5.w};
#pragma unroll
        for (int i = 0; i < 8; ++i) {
            unsigned j = ((c[i] == 0.0f) ? 2u : 0u) | ((o[i] == 0.0f) ? 1u : 0u);
            bool b0 = (j & 1u) != 0u;
            bool b1 = (j & 2u) != 0u;
            float k_lo = b0 ? k1 : k0;
            float k_hi = b0 ? k3 : k2;
            float a_lo = b0 ? a1 : a0;
            float a_hi = b0 ? a3 : a2;
            float gb = b0 ? g1 : g0;
            float kj = b1 ? k_hi : k_lo;
            float kjR = b1 ? k_lo : k_hi;
            float aj = b1 ? a_hi : a_lo;
            float ajR = b1 ? a_lo : a_hi;
            float dL = kj - sL;
            float dR = kjR - sR;
            float v = b1 ? dR : dL;
            sL = fmaf(dL * aj, lam, sL);
            sR = fmaf(dR * ajR, lam, sR);
            lam = fmaf(fabsf(v) - lam, gb, lam);
            reinterpret_cast<float2*>(op)[w * 8 + i] = make_float2(sL, sR);
        }
    }
}

extern "C" void kernel_launch(void* const* d_in, const int* in_sizes, int n_in,
                              void* d_out, int out_size, void* d_ws, size_t ws_size,
                              hipStream_t stream) {
    const float* inp          = (const float*)d_in[0];
    const float* alpha_logits = (const float*)d_in[1];
    const float* gamma_logits = (const float*)d_in[2];
    const float* k_vals       = (const float*)d_in[3];
    float* out = (float*)d_out;

    size_t need = (size_t)NG4 * BS * 4 * sizeof(unsigned int); // 2 MiB
    if (ws_size >= need) {
        unsigned int* packed = (unsigned int*)d_ws;
        int total = BS * NW;
        pack_kernel<<<(total + 255) / 256, 256, 0, stream>>>(inp, packed);
        scan2<<<BS / 64, 64, 0, stream>>>((const uint4*)packed, alpha_logits, gamma_logits,
                                          k_vals, out);
    } else {
        scan_fused<<<BS / 64, 64, 0, stream>>>(inp, alpha_logits, gamma_logits, k_vals, out);
    }
}